// Round 1
// baseline (514.156 us; speedup 1.0000x reference)
//
#include <hip/hip_runtime.h>
#include <hip/hip_bf16.h>
#include <float.h>

#define NN 50000
#define KNB 32
#define INC 128
#define HC 64
#define EDD 32
#define H2C 128

// ---------------------------------------------------------------------------
// K1: src = x @ w_src.T, dstf = x @ w_dst.T   [N,128] -> [N,64] each
// block: 256 threads = 2 nodes x 128 channels (c<64 -> src ch c, else dst ch c-64)
// ---------------------------------------------------------------------------
__global__ __launch_bounds__(256) void k_node_linear(
    const float* __restrict__ x, const float* __restrict__ w_src,
    const float* __restrict__ w_dst, float* __restrict__ srcf,
    float* __restrict__ dstf)
{
    __shared__ __align__(16) float wsh[2][64][132];  // stride 132 floats: 33 words ≡ 1 mod 32 -> bank=(row+j)%32, 16B aligned
    __shared__ __align__(16) float xsh[2][128];

    for (int i = threadIdx.x; i < 64 * 128; i += 256) {
        int r = i >> 7, c = i & 127;
        wsh[0][r][c] = w_src[i];
        wsh[1][r][c] = w_dst[i];
    }
    __syncthreads();

    const int c     = threadIdx.x & 127;
    const int which = (c >= 64) ? 1 : 0;
    const int row   = c & 63;
    const int nl    = threadIdx.x >> 7;

    for (int base = blockIdx.x * 2; base < NN; base += gridDim.x * 2) {
        int n = base + nl;
        __syncthreads();
        if (n < NN) xsh[nl][c] = x[n * INC + c];
        __syncthreads();
        if (n < NN) {
            const float* wrow = &wsh[which][row][0];
            const float* xrow = &xsh[nl][0];
            float acc = 0.f;
            #pragma unroll
            for (int j4 = 0; j4 < INC / 4; ++j4) {
                float4 wv = *(const float4*)(wrow + j4 * 4);
                float4 xv = *(const float4*)(xrow + j4 * 4);
                acc += wv.x * xv.x + wv.y * xv.y + wv.z * xv.z + wv.w * xv.w;
            }
            if (which == 0) srcf[n * HC + row] = acc;
            else            dstf[n * HC + row] = acc;
        }
    }
}

// ---------------------------------------------------------------------------
// K2: fused edge projection + ReLU+eps + per-node per-channel softmax agg.
// One wave (64 lanes) per node; lane = channel h. Edges of node n are
// exactly [n*K, n*K+K) with validity nbr[n*K+k] >= 0.
// ---------------------------------------------------------------------------
__global__ __launch_bounds__(256) void k_edge_agg(
    const float* __restrict__ srcf, const float* __restrict__ dstf,
    const float* __restrict__ edge_attr, const float* __restrict__ w_edge,
    const int* __restrict__ esrc, const int* __restrict__ nbr,
    float* __restrict__ outf)
{
    __shared__ __align__(16) float attr[4][KNB][EDD];  // 16KB, per-wave private tile

    const int wave = threadIdx.x >> 6;
    const int lane = threadIdx.x & 63;
    const int n    = blockIdx.x * 4 + wave;   // grid = 12500, NN = 50000 exactly

    // lane h keeps its w_edge row in registers
    float we[EDD];
    #pragma unroll
    for (int d4 = 0; d4 < EDD / 4; ++d4) {
        float4 v = *(const float4*)&w_edge[lane * EDD + d4 * 4];
        we[d4 * 4 + 0] = v.x; we[d4 * 4 + 1] = v.y;
        we[d4 * 4 + 2] = v.z; we[d4 * 4 + 3] = v.w;
    }

    // stage this node's 32x32 edge_attr tile (contiguous 4KB) into LDS
    const float4* ap = (const float4*)&edge_attr[(size_t)n * KNB * EDD];
    float4* as = (float4*)&attr[wave][0][0];
    #pragma unroll
    for (int i = 0; i < 4; ++i) as[i * 64 + lane] = ap[i * 64 + lane];

    // wave-uniform validity mask
    int nbv = nbr[n * KNB + (lane & 31)];
    unsigned long long bm = __ballot((lane < 32) && (nbv >= 0));
    unsigned int vmask = (unsigned int)bm;

    __syncthreads();

    float msg[KNB];
    #pragma unroll
    for (int k = 0; k < KNB; ++k) {
        int e = n * KNB + k;
        int s = esrc[e];                       // wave-uniform
        float xj = srcf[s * HC + lane];        // coalesced 256B gather
        float acc = 0.f;
        #pragma unroll
        for (int d = 0; d < EDD; ++d) acc += attr[wave][k][d] * we[d];
        float m = xj + acc;
        m = (m > 0.f ? m : 0.f) + 1e-7f;
        msg[k] = m;
    }

    float mx = -FLT_MAX;
    #pragma unroll
    for (int k = 0; k < KNB; ++k) {
        float v = ((vmask >> k) & 1u) ? msg[k] : -FLT_MAX;
        mx = fmaxf(mx, v);
    }
    float se = 0.f, wsum = 0.f;
    #pragma unroll
    for (int k = 0; k < KNB; ++k) {
        float valid = ((vmask >> k) & 1u) ? 1.f : 0.f;
        float t = __expf(msg[k] - mx) * valid;
        se   += t;
        wsum += msg[k] * t;
    }
    float outv = wsum / (se + 1e-16f) + dstf[n * HC + lane];
    outf[n * HC + lane] = outv;
}

// ---------------------------------------------------------------------------
// K3: h = out @ w1.T  [N,64]->[N,128], plus per-block partial sums/sumsq per
// channel for BatchNorm stats.
// ---------------------------------------------------------------------------
__global__ __launch_bounds__(256) void k_h_partial(
    const float* __restrict__ outf, const float* __restrict__ w1,
    float* __restrict__ h, float* __restrict__ partials)
{
    __shared__ float w1sh[H2C][65];   // stride 65 ≡ 1 mod 32 -> bank=(row+j)%32
    __shared__ float osh[2][64];
    __shared__ float red[256];

    const int t = threadIdx.x;
    for (int i = t; i < H2C * HC; i += 256) w1sh[i >> 6][i & 63] = w1[i];

    const int c  = t & 127;
    const int nl = t >> 7;
    float sacc = 0.f, qacc = 0.f;
    __syncthreads();

    for (int base = blockIdx.x * 2; base < NN; base += gridDim.x * 2) {
        __syncthreads();
        if (t < 128) {
            int node = t >> 6, j = t & 63;
            int n = base + node;
            if (n < NN) osh[node][j] = outf[n * HC + j];
        }
        __syncthreads();
        int n = base + nl;
        if (n < NN) {
            float acc = 0.f;
            #pragma unroll
            for (int j = 0; j < HC; ++j) acc += osh[nl][j] * w1sh[c][j];
            h[n * H2C + c] = acc;
            sacc += acc;
            qacc += acc * acc;
        }
    }

    red[t] = sacc;
    __syncthreads();
    float sumv = (t < 128) ? (red[t] + red[t + 128]) : 0.f;
    __syncthreads();
    red[t] = qacc;
    __syncthreads();
    if (t < 128) {
        float sumq = red[t] + red[t + 128];
        partials[blockIdx.x * 256 + t]       = sumv;
        partials[blockIdx.x * 256 + 128 + t] = sumq;
    }
}

// ---------------------------------------------------------------------------
// K4: reduce partials -> BN scale/bias
// ---------------------------------------------------------------------------
__global__ __launch_bounds__(256) void k_bn_finalize(
    const float* __restrict__ partials, int nblk,
    const float* __restrict__ gamma, const float* __restrict__ beta,
    float* __restrict__ sb)
{
    const int t = threadIdx.x;
    float acc = 0.f;
    for (int b = 0; b < nblk; ++b) acc += partials[b * 256 + t];
    __shared__ float red[256];
    red[t] = acc;
    __syncthreads();
    if (t < 128) {
        float s = red[t];
        float q = red[t + 128];
        float mean = s / (float)NN;
        float var  = q / (float)NN - mean * mean;
        float scale = gamma[t] * rsqrtf(var + 1e-5f);
        float bias  = beta[t] - mean * scale;
        sb[t]       = scale;
        sb[128 + t] = bias;
    }
}

// ---------------------------------------------------------------------------
// K5: out2 = relu(h*scale+bias) @ w2.T  [N,128]->[N,64]
// ---------------------------------------------------------------------------
__global__ __launch_bounds__(256) void k_out(
    const float* __restrict__ h, const float* __restrict__ w2,
    const float* __restrict__ sb, float* __restrict__ out)
{
    __shared__ float w2sh[HC][129];   // stride 129 ≡ 1 mod 32
    __shared__ float hsh[4][128];
    __shared__ float ssh[128], bsh[128];

    const int t = threadIdx.x;
    for (int i = t; i < HC * H2C; i += 256) w2sh[i >> 7][i & 127] = w2[i];
    if (t < 128) { ssh[t] = sb[t]; bsh[t] = sb[128 + t]; }
    __syncthreads();

    const int co = t & 63;
    const int nl = t >> 6;

    for (int base = blockIdx.x * 4; base < NN; base += gridDim.x * 4) {
        __syncthreads();
        #pragma unroll
        for (int i = 0; i < 2; ++i) {
            int idx  = i * 256 + t;       // 0..511, coalesced
            int node = idx >> 7, j = idx & 127;
            int n = base + node;
            if (n < NN) {
                float v = h[n * H2C + j] * ssh[j] + bsh[j];
                hsh[node][j] = v > 0.f ? v : 0.f;
            }
        }
        __syncthreads();
        int n = base + nl;
        if (n < NN) {
            float acc = 0.f;
            #pragma unroll
            for (int j = 0; j < H2C; ++j) acc += hsh[nl][j] * w2sh[co][j];
            out[n * HC + co] = acc;
        }
    }
}

// ---------------------------------------------------------------------------
extern "C" void kernel_launch(void* const* d_in, const int* in_sizes, int n_in,
                              void* d_out, int out_size, void* d_ws, size_t ws_size,
                              hipStream_t stream) {
    const float* x         = (const float*)d_in[0];
    const float* edge_attr = (const float*)d_in[1];
    const float* w_src     = (const float*)d_in[2];
    const float* w_dst     = (const float*)d_in[3];
    const float* w_edge    = (const float*)d_in[4];
    const float* w1        = (const float*)d_in[5];
    const float* gamma     = (const float*)d_in[6];
    const float* beta      = (const float*)d_in[7];
    const float* w2        = (const float*)d_in[8];
    const int*   eidx      = (const int*)d_in[9];    // [2][E], row 0 = src
    const int*   nbr       = (const int*)d_in[10];   // [N][K]

    float* ws   = (float*)d_ws;
    float* srcf = ws;                    // N*64   = 3.2M
    float* dstf = ws + 3200000;          // N*64
    float* outf = ws + 6400000;          // N*64
    float* h    = ws + 9600000;          // N*128  = 6.4M
    float* part = ws + 16000000;         // 512*256
    float* sb   = ws + 16131072;         // 256

    hipLaunchKernelGGL(k_node_linear, dim3(512),   dim3(256), 0, stream,
                       x, w_src, w_dst, srcf, dstf);
    hipLaunchKernelGGL(k_edge_agg,    dim3(12500), dim3(256), 0, stream,
                       srcf, dstf, edge_attr, w_edge, eidx, nbr, outf);
    hipLaunchKernelGGL(k_h_partial,   dim3(512),   dim3(256), 0, stream,
                       outf, w1, h, part);
    hipLaunchKernelGGL(k_bn_finalize, dim3(1),     dim3(256), 0, stream,
                       part, 512, gamma, beta, sb);
    hipLaunchKernelGGL(k_out,         dim3(512),   dim3(256), 0, stream,
                       h, w2, sb, (float*)d_out);
}

// Round 2
// 396.355 us; speedup vs baseline: 1.2972x; 1.2972x over previous
//
#include <hip/hip_runtime.h>
#include <hip/hip_bf16.h>
#include <float.h>

#define NN 50000
#define KNB 32
#define INC 128
#define HC 64
#define EDD 32
#define H2C 128

typedef __attribute__((ext_vector_type(8))) short bf16x8;
typedef __attribute__((ext_vector_type(4))) float f32x4;

__device__ __forceinline__ short f2bf(float f) {
    unsigned u = __builtin_bit_cast(unsigned, f);
    u += 0x7fffu + ((u >> 16) & 1u);          // RTNE
    return (short)(u >> 16);
}

// ---------------------------------------------------------------------------
// K1: src = x @ w_src.T, dstf = x @ w_dst.T   [N,128] -> [N,64] each
// ---------------------------------------------------------------------------
__global__ __launch_bounds__(256) void k_node_linear(
    const float* __restrict__ x, const float* __restrict__ w_src,
    const float* __restrict__ w_dst, float* __restrict__ srcf,
    float* __restrict__ dstf)
{
    __shared__ __align__(16) float wsh[2][64][132];
    __shared__ __align__(16) float xsh[2][128];

    for (int i = threadIdx.x; i < 64 * 128; i += 256) {
        int r = i >> 7, c = i & 127;
        wsh[0][r][c] = w_src[i];
        wsh[1][r][c] = w_dst[i];
    }
    __syncthreads();

    const int c     = threadIdx.x & 127;
    const int which = (c >= 64) ? 1 : 0;
    const int row   = c & 63;
    const int nl    = threadIdx.x >> 7;

    for (int base = blockIdx.x * 2; base < NN; base += gridDim.x * 2) {
        int n = base + nl;
        __syncthreads();
        if (n < NN) xsh[nl][c] = x[n * INC + c];
        __syncthreads();
        if (n < NN) {
            const float* wrow = &wsh[which][row][0];
            const float* xrow = &xsh[nl][0];
            float acc = 0.f;
            #pragma unroll
            for (int j4 = 0; j4 < INC / 4; ++j4) {
                float4 wv = *(const float4*)(wrow + j4 * 4);
                float4 xv = *(const float4*)(xrow + j4 * 4);
                acc += wv.x * xv.x + wv.y * xv.y + wv.z * xv.z + wv.w * xv.w;
            }
            if (which == 0) srcf[n * HC + row] = acc;
            else            dstf[n * HC + row] = acc;
        }
    }
}

// ---------------------------------------------------------------------------
// K2 (MFMA): fused edge projection + ReLU+eps + per-node softmax aggregation.
// One wave per node. P[k][c] = attr(32x32) @ w_edge^T(32x64) via 8x
// mfma_f32_16x16x32_bf16. No LDS, no __syncthreads.
// Fragment layout (m89-verified): A row=lane&15, k=(lane>>4)*8+j;
// B col=lane&15, k=(lane>>4)*8+j; C/D row=(lane>>4)*4+reg, col=lane&15.
// ---------------------------------------------------------------------------
__global__ __launch_bounds__(256) void k_edge_agg_mfma(
    const float* __restrict__ srcf, const float* __restrict__ dstf,
    const float* __restrict__ edge_attr, const float* __restrict__ w_edge,
    const int* __restrict__ esrc, const int* __restrict__ nbr,
    float* __restrict__ outf)
{
    const int lane = threadIdx.x & 63;
    const int wave = threadIdx.x >> 6;
    const int n    = blockIdx.x * 4 + wave;     // grid 12500 * 4 = 50000 exactly

    const int lr = lane & 15;   // row (A) / col (B,C) within 16-tile
    const int lg = lane >> 4;   // k-group

    // B fragments: w_edge[16*nt + lr][lg*8 + j]  (8KB matrix, L2-resident)
    bf16x8 bfrag[4];
    #pragma unroll
    for (int nt = 0; nt < 4; ++nt) {
        const float* wp = &w_edge[(nt * 16 + lr) * EDD + lg * 8];
        float4 w0 = *(const float4*)wp;
        float4 w1 = *(const float4*)(wp + 4);
        bfrag[nt][0] = f2bf(w0.x); bfrag[nt][1] = f2bf(w0.y);
        bfrag[nt][2] = f2bf(w0.z); bfrag[nt][3] = f2bf(w0.w);
        bfrag[nt][4] = f2bf(w1.x); bfrag[nt][5] = f2bf(w1.y);
        bfrag[nt][6] = f2bf(w1.z); bfrag[nt][7] = f2bf(w1.w);
    }

    // A fragments: this node's 32x32 edge_attr tile (contiguous 4KB)
    const float* ab = edge_attr + (size_t)n * KNB * EDD;
    bf16x8 afrag[2];
    #pragma unroll
    for (int mt = 0; mt < 2; ++mt) {
        const float* ap = ab + (mt * 16 + lr) * EDD + lg * 8;
        float4 a0 = *(const float4*)ap;
        float4 a1 = *(const float4*)(ap + 4);
        afrag[mt][0] = f2bf(a0.x); afrag[mt][1] = f2bf(a0.y);
        afrag[mt][2] = f2bf(a0.z); afrag[mt][3] = f2bf(a0.w);
        afrag[mt][4] = f2bf(a1.x); afrag[mt][5] = f2bf(a1.y);
        afrag[mt][6] = f2bf(a1.z); afrag[mt][7] = f2bf(a1.w);
    }

    // wave-uniform validity mask (valid edges are a prefix, deg >= 16)
    int nbv = nbr[n * KNB + (lane & 31)];
    unsigned long long bm = __ballot((lane < 32) && (nbv >= 0));
    unsigned int vmask = (unsigned int)bm;

    // source indices for this lane's 8 edge slots
    int sidx[2][4];
    #pragma unroll
    for (int mt = 0; mt < 2; ++mt)
        #pragma unroll
        for (int r = 0; r < 4; ++r)
            sidx[mt][r] = esrc[n * KNB + mt * 16 + lg * 4 + r];

    // projection: p[mt][nt][r] = P[16mt + lg*4 + r][16nt + lr]
    f32x4 p[2][4];
    #pragma unroll
    for (int mt = 0; mt < 2; ++mt)
        #pragma unroll
        for (int nt = 0; nt < 4; ++nt) {
            f32x4 z = {0.f, 0.f, 0.f, 0.f};
            p[mt][nt] = __builtin_amdgcn_mfma_f32_16x16x32_bf16(
                afrag[mt], bfrag[nt], z, 0, 0, 0);
        }

    // msg = relu(x_j + proj) + eps
    float msg[2][4][4];   // [mt][r][nt]
    float vf[2][4];
    #pragma unroll
    for (int mt = 0; mt < 2; ++mt)
        #pragma unroll
        for (int r = 0; r < 4; ++r) {
            int k = mt * 16 + lg * 4 + r;
            vf[mt][r] = ((vmask >> k) & 1u) ? 1.f : 0.f;
            const float* sp = &srcf[(size_t)sidx[mt][r] * HC + lr];
            #pragma unroll
            for (int nt = 0; nt < 4; ++nt) {
                float xj = sp[nt * 16];
                float m = p[mt][nt][r] + xj;
                msg[mt][r][nt] = fmaxf(m, 0.f) + 1e-7f;
            }
        }

    // per-channel softmax-weighted sum; channel c = 16*nt + lr lives in
    // lanes {lr, lr+16, lr+32, lr+48} -> reduce via shfl_xor 16,32
    float res[4];
    #pragma unroll
    for (int nt = 0; nt < 4; ++nt) {
        float lm = -FLT_MAX;
        #pragma unroll
        for (int mt = 0; mt < 2; ++mt)
            #pragma unroll
            for (int r = 0; r < 4; ++r) {
                float v = (vf[mt][r] > 0.f) ? msg[mt][r][nt] : -FLT_MAX;
                lm = fmaxf(lm, v);
            }
        lm = fmaxf(lm, __shfl_xor(lm, 16, 64));
        lm = fmaxf(lm, __shfl_xor(lm, 32, 64));
        float se = 0.f, ws = 0.f;
        #pragma unroll
        for (int mt = 0; mt < 2; ++mt)
            #pragma unroll
            for (int r = 0; r < 4; ++r) {
                float t = __expf(msg[mt][r][nt] - lm) * vf[mt][r];
                se += t;
                ws += msg[mt][r][nt] * t;
            }
        se += __shfl_xor(se, 16, 64); ws += __shfl_xor(ws, 16, 64);
        se += __shfl_xor(se, 32, 64); ws += __shfl_xor(ws, 32, 64);
        res[nt] = ws / (se + 1e-16f);
    }

    // lane writes channel == lane (nt = lane>>4): constant-index select
    float r01 = (lg & 1) ? res[1] : res[0];
    float r23 = (lg & 1) ? res[3] : res[2];
    float rr  = (lg & 2) ? r23 : r01;
    outf[n * HC + lane] = rr + dstf[n * HC + lane];
}

// ---------------------------------------------------------------------------
// K3: h = out @ w1.T  [N,64]->[N,128] + per-block BN partial sums
// ---------------------------------------------------------------------------
__global__ __launch_bounds__(256) void k_h_partial(
    const float* __restrict__ outf, const float* __restrict__ w1,
    float* __restrict__ h, float* __restrict__ partials)
{
    __shared__ float w1sh[H2C][65];
    __shared__ float osh[2][64];
    __shared__ float red[256];

    const int t = threadIdx.x;
    for (int i = t; i < H2C * HC; i += 256) w1sh[i >> 6][i & 63] = w1[i];

    const int c  = t & 127;
    const int nl = t >> 7;
    float sacc = 0.f, qacc = 0.f;
    __syncthreads();

    for (int base = blockIdx.x * 2; base < NN; base += gridDim.x * 2) {
        __syncthreads();
        if (t < 128) {
            int node = t >> 6, j = t & 63;
            int n = base + node;
            if (n < NN) osh[node][j] = outf[n * HC + j];
        }
        __syncthreads();
        int n = base + nl;
        if (n < NN) {
            float acc = 0.f;
            #pragma unroll
            for (int j = 0; j < HC; ++j) acc += osh[nl][j] * w1sh[c][j];
            h[n * H2C + c] = acc;
            sacc += acc;
            qacc += acc * acc;
        }
    }

    red[t] = sacc;
    __syncthreads();
    float sumv = (t < 128) ? (red[t] + red[t + 128]) : 0.f;
    __syncthreads();
    red[t] = qacc;
    __syncthreads();
    if (t < 128) {
        float sumq = red[t] + red[t + 128];
        partials[blockIdx.x * 256 + t]       = sumv;
        partials[blockIdx.x * 256 + 128 + t] = sumq;
    }
}

// ---------------------------------------------------------------------------
// K4: reduce partials -> BN scale/bias
// ---------------------------------------------------------------------------
__global__ __launch_bounds__(256) void k_bn_finalize(
    const float* __restrict__ partials, int nblk,
    const float* __restrict__ gamma, const float* __restrict__ beta,
    float* __restrict__ sb)
{
    const int t = threadIdx.x;
    float acc = 0.f;
    for (int b = 0; b < nblk; ++b) acc += partials[b * 256 + t];
    __shared__ float red[256];
    red[t] = acc;
    __syncthreads();
    if (t < 128) {
        float s = red[t];
        float q = red[t + 128];
        float mean = s / (float)NN;
        float var  = q / (float)NN - mean * mean;
        float scale = gamma[t] * rsqrtf(var + 1e-5f);
        float bias  = beta[t] - mean * scale;
        sb[t]       = scale;
        sb[128 + t] = bias;
    }
}

// ---------------------------------------------------------------------------
// K5: out2 = relu(h*scale+bias) @ w2.T  [N,128]->[N,64]
// ---------------------------------------------------------------------------
__global__ __launch_bounds__(256) void k_out(
    const float* __restrict__ h, const float* __restrict__ w2,
    const float* __restrict__ sb, float* __restrict__ out)
{
    __shared__ float w2sh[HC][129];
    __shared__ float hsh[4][128];
    __shared__ float ssh[128], bsh[128];

    const int t = threadIdx.x;
    for (int i = t; i < HC * H2C; i += 256) w2sh[i >> 7][i & 127] = w2[i];
    if (t < 128) { ssh[t] = sb[t]; bsh[t] = sb[128 + t]; }
    __syncthreads();

    const int co = t & 63;
    const int nl = t >> 6;

    for (int base = blockIdx.x * 4; base < NN; base += gridDim.x * 4) {
        __syncthreads();
        #pragma unroll
        for (int i = 0; i < 2; ++i) {
            int idx  = i * 256 + t;
            int node = idx >> 7, j = idx & 127;
            int n = base + node;
            if (n < NN) {
                float v = h[n * H2C + j] * ssh[j] + bsh[j];
                hsh[node][j] = v > 0.f ? v : 0.f;
            }
        }
        __syncthreads();
        int n = base + nl;
        if (n < NN) {
            float acc = 0.f;
            #pragma unroll
            for (int j = 0; j < H2C; ++j) acc += hsh[nl][j] * w2sh[co][j];
            out[n * HC + co] = acc;
        }
    }
}

// ---------------------------------------------------------------------------
extern "C" void kernel_launch(void* const* d_in, const int* in_sizes, int n_in,
                              void* d_out, int out_size, void* d_ws, size_t ws_size,
                              hipStream_t stream) {
    const float* x         = (const float*)d_in[0];
    const float* edge_attr = (const float*)d_in[1];
    const float* w_src     = (const float*)d_in[2];
    const float* w_dst     = (const float*)d_in[3];
    const float* w_edge    = (const float*)d_in[4];
    const float* w1        = (const float*)d_in[5];
    const float* gamma     = (const float*)d_in[6];
    const float* beta      = (const float*)d_in[7];
    const float* w2        = (const float*)d_in[8];
    const int*   eidx      = (const int*)d_in[9];    // [2][E], row 0 = src
    const int*   nbr       = (const int*)d_in[10];   // [N][K]

    float* ws   = (float*)d_ws;
    float* srcf = ws;                    // N*64
    float* dstf = ws + 3200000;          // N*64
    float* outf = ws + 6400000;          // N*64
    float* h    = ws + 9600000;          // N*128
    float* part = ws + 16000000;         // 512*256
    float* sb   = ws + 16131072;         // 256

    hipLaunchKernelGGL(k_node_linear,  dim3(512),   dim3(256), 0, stream,
                       x, w_src, w_dst, srcf, dstf);
    hipLaunchKernelGGL(k_edge_agg_mfma, dim3(12500), dim3(256), 0, stream,
                       srcf, dstf, edge_attr, w_edge, eidx, nbr, outf);
    hipLaunchKernelGGL(k_h_partial,    dim3(512),   dim3(256), 0, stream,
                       outf, w1, h, part);
    hipLaunchKernelGGL(k_bn_finalize,  dim3(1),     dim3(256), 0, stream,
                       part, 512, gamma, beta, sb);
    hipLaunchKernelGGL(k_out,          dim3(512),   dim3(256), 0, stream,
                       h, w2, sb, (float*)d_out);
}

// Round 3
// 289.115 us; speedup vs baseline: 1.7784x; 1.3709x over previous
//
#include <hip/hip_runtime.h>
#include <hip/hip_bf16.h>
#include <float.h>

#define NN 50000
#define KNB 32
#define INC 128
#define HC 64
#define EDD 32
#define H2C 128

typedef __attribute__((ext_vector_type(8))) short bf16x8;
typedef __attribute__((ext_vector_type(4))) float f32x4;

__device__ __forceinline__ short f2bf(float f) {
    unsigned u = __builtin_bit_cast(unsigned, f);
    u += 0x7fffu + ((u >> 16) & 1u);          // RTNE
    return (short)(u >> 16);
}

// ---------------------------------------------------------------------------
// K1: src = x @ w_src.T, dstf = x @ w_dst.T   [N,128] -> [N,64] each
// ---------------------------------------------------------------------------
__global__ __launch_bounds__(256) void k_node_linear(
    const float* __restrict__ x, const float* __restrict__ w_src,
    const float* __restrict__ w_dst, float* __restrict__ srcf,
    float* __restrict__ dstf)
{
    __shared__ __align__(16) float wsh[2][64][132];
    __shared__ __align__(16) float xsh[2][128];

    for (int i = threadIdx.x; i < 64 * 128; i += 256) {
        int r = i >> 7, c = i & 127;
        wsh[0][r][c] = w_src[i];
        wsh[1][r][c] = w_dst[i];
    }
    __syncthreads();

    const int c     = threadIdx.x & 127;
    const int which = (c >= 64) ? 1 : 0;
    const int row   = c & 63;
    const int nl    = threadIdx.x >> 7;

    for (int base = blockIdx.x * 2; base < NN; base += gridDim.x * 2) {
        int n = base + nl;
        __syncthreads();
        if (n < NN) xsh[nl][c] = x[n * INC + c];
        __syncthreads();
        if (n < NN) {
            const float* wrow = &wsh[which][row][0];
            const float* xrow = &xsh[nl][0];
            float acc = 0.f;
            #pragma unroll
            for (int j4 = 0; j4 < INC / 4; ++j4) {
                float4 wv = *(const float4*)(wrow + j4 * 4);
                float4 xv = *(const float4*)(xrow + j4 * 4);
                acc += wv.x * xv.x + wv.y * xv.y + wv.z * xv.z + wv.w * xv.w;
            }
            if (which == 0) srcf[n * HC + row] = acc;
            else            dstf[n * HC + row] = acc;
        }
    }
}

// ---------------------------------------------------------------------------
// K2 (MFMA): fused edge projection + ReLU+eps + per-node softmax aggregation.
// ---------------------------------------------------------------------------
__global__ __launch_bounds__(256) void k_edge_agg_mfma(
    const float* __restrict__ srcf, const float* __restrict__ dstf,
    const float* __restrict__ edge_attr, const float* __restrict__ w_edge,
    const int* __restrict__ esrc, const int* __restrict__ nbr,
    float* __restrict__ outf)
{
    const int lane = threadIdx.x & 63;
    const int wave = threadIdx.x >> 6;
    const int n    = blockIdx.x * 4 + wave;     // grid 12500 * 4 = 50000 exactly

    const int lr = lane & 15;   // row (A) / col (B,C) within 16-tile
    const int lg = lane >> 4;   // k-group

    // B fragments: w_edge[16*nt + lr][lg*8 + j]
    bf16x8 bfrag[4];
    #pragma unroll
    for (int nt = 0; nt < 4; ++nt) {
        const float* wp = &w_edge[(nt * 16 + lr) * EDD + lg * 8];
        float4 w0 = *(const float4*)wp;
        float4 w1 = *(const float4*)(wp + 4);
        bfrag[nt][0] = f2bf(w0.x); bfrag[nt][1] = f2bf(w0.y);
        bfrag[nt][2] = f2bf(w0.z); bfrag[nt][3] = f2bf(w0.w);
        bfrag[nt][4] = f2bf(w1.x); bfrag[nt][5] = f2bf(w1.y);
        bfrag[nt][6] = f2bf(w1.z); bfrag[nt][7] = f2bf(w1.w);
    }

    // A fragments: this node's 32x32 edge_attr tile (contiguous 4KB)
    const float* ab = edge_attr + (size_t)n * KNB * EDD;
    bf16x8 afrag[2];
    #pragma unroll
    for (int mt = 0; mt < 2; ++mt) {
        const float* ap = ab + (mt * 16 + lr) * EDD + lg * 8;
        float4 a0 = *(const float4*)ap;
        float4 a1 = *(const float4*)(ap + 4);
        afrag[mt][0] = f2bf(a0.x); afrag[mt][1] = f2bf(a0.y);
        afrag[mt][2] = f2bf(a0.z); afrag[mt][3] = f2bf(a0.w);
        afrag[mt][4] = f2bf(a1.x); afrag[mt][5] = f2bf(a1.y);
        afrag[mt][6] = f2bf(a1.z); afrag[mt][7] = f2bf(a1.w);
    }

    // wave-uniform validity mask (valid edges are a prefix of each node's K)
    int nbv = nbr[n * KNB + (lane & 31)];
    unsigned long long bm = __ballot((lane < 32) && (nbv >= 0));
    unsigned int vmask = (unsigned int)bm;

    // source indices for this lane's 8 edge slots
    int sidx[2][4];
    #pragma unroll
    for (int mt = 0; mt < 2; ++mt)
        #pragma unroll
        for (int r = 0; r < 4; ++r)
            sidx[mt][r] = esrc[n * KNB + mt * 16 + lg * 4 + r];

    // projection: p[mt][nt][r] = P[16mt + lg*4 + r][16nt + lr]
    f32x4 p[2][4];
    #pragma unroll
    for (int mt = 0; mt < 2; ++mt)
        #pragma unroll
        for (int nt = 0; nt < 4; ++nt) {
            f32x4 z = {0.f, 0.f, 0.f, 0.f};
            p[mt][nt] = __builtin_amdgcn_mfma_f32_16x16x32_bf16(
                afrag[mt], bfrag[nt], z, 0, 0, 0);
        }

    // msg = relu(x_j + proj) + eps
    float msg[2][4][4];   // [mt][r][nt]
    float vf[2][4];
    #pragma unroll
    for (int mt = 0; mt < 2; ++mt)
        #pragma unroll
        for (int r = 0; r < 4; ++r) {
            int k = mt * 16 + lg * 4 + r;
            vf[mt][r] = ((vmask >> k) & 1u) ? 1.f : 0.f;
            const float* sp = &srcf[(size_t)sidx[mt][r] * HC + lr];
            #pragma unroll
            for (int nt = 0; nt < 4; ++nt) {
                float xj = sp[nt * 16];
                float m = p[mt][nt][r] + xj;
                msg[mt][r][nt] = fmaxf(m, 0.f) + 1e-7f;
            }
        }

    // per-channel softmax-weighted sum; channel c = 16*nt + lr lives in
    // lanes {lr, lr+16, lr+32, lr+48} -> reduce via shfl_xor 16,32
    float res[4];
    #pragma unroll
    for (int nt = 0; nt < 4; ++nt) {
        float lm = -FLT_MAX;
        #pragma unroll
        for (int mt = 0; mt < 2; ++mt)
            #pragma unroll
            for (int r = 0; r < 4; ++r) {
                float v = (vf[mt][r] > 0.f) ? msg[mt][r][nt] : -FLT_MAX;
                lm = fmaxf(lm, v);
            }
        lm = fmaxf(lm, __shfl_xor(lm, 16, 64));
        lm = fmaxf(lm, __shfl_xor(lm, 32, 64));
        float se = 0.f, ws = 0.f;
        #pragma unroll
        for (int mt = 0; mt < 2; ++mt)
            #pragma unroll
            for (int r = 0; r < 4; ++r) {
                float t = __expf(msg[mt][r][nt] - lm) * vf[mt][r];
                se += t;
                ws += msg[mt][r][nt] * t;
            }
        se += __shfl_xor(se, 16, 64); ws += __shfl_xor(ws, 16, 64);
        se += __shfl_xor(se, 32, 64); ws += __shfl_xor(ws, 32, 64);
        res[nt] = ws / (se + 1e-16f);
    }

    float r01 = (lg & 1) ? res[1] : res[0];
    float r23 = (lg & 1) ? res[3] : res[2];
    float rr  = (lg & 2) ? r23 : r01;
    outf[n * HC + lane] = rr + dstf[n * HC + lane];
}

// ---------------------------------------------------------------------------
// K3: h = out @ w1.T  [N,64]->[N,128] + per-block BN partial sums
// ---------------------------------------------------------------------------
__global__ __launch_bounds__(256) void k_h_partial(
    const float* __restrict__ outf, const float* __restrict__ w1,
    float* __restrict__ h, float* __restrict__ partials)
{
    __shared__ float w1sh[H2C][65];
    __shared__ float osh[2][64];
    __shared__ float red[256];

    const int t = threadIdx.x;
    for (int i = t; i < H2C * HC; i += 256) w1sh[i >> 6][i & 63] = w1[i];

    const int c  = t & 127;
    const int nl = t >> 7;
    float sacc = 0.f, qacc = 0.f;
    __syncthreads();

    for (int base = blockIdx.x * 2; base < NN; base += gridDim.x * 2) {
        __syncthreads();
        if (t < 128) {
            int node = t >> 6, j = t & 63;
            int n = base + node;
            if (n < NN) osh[node][j] = outf[n * HC + j];
        }
        __syncthreads();
        int n = base + nl;
        if (n < NN) {
            float acc = 0.f;
            #pragma unroll
            for (int j = 0; j < HC; ++j) acc += osh[nl][j] * w1sh[c][j];
            h[n * H2C + c] = acc;
            sacc += acc;
            qacc += acc * acc;
        }
    }

    red[t] = sacc;
    __syncthreads();
    float sumv = (t < 128) ? (red[t] + red[t + 128]) : 0.f;
    __syncthreads();
    red[t] = qacc;
    __syncthreads();
    if (t < 128) {
        float sumq = red[t] + red[t + 128];
        partials[blockIdx.x * 256 + t]       = sumv;
        partials[blockIdx.x * 256 + 128 + t] = sumq;
    }
}

// ---------------------------------------------------------------------------
// K4: reduce partials -> BN scale/bias. 1024 threads: 16 row-slices x 64
// float4 columns; latency-hidden vector loads + LDS tree reduce.
// ---------------------------------------------------------------------------
__global__ __launch_bounds__(1024) void k_bn_finalize(
    const float* __restrict__ partials, int nblk,
    const float* __restrict__ gamma, const float* __restrict__ beta,
    float* __restrict__ sb)
{
    const int t = threadIdx.x;
    const int f = t & 63;    // float4 column within 256-float row
    const int g = t >> 6;    // slice 0..15

    float4 acc = {0.f, 0.f, 0.f, 0.f};
    for (int b = g; b < nblk; b += 16) {
        float4 v = *(const float4*)&partials[b * 256 + f * 4];
        acc.x += v.x; acc.y += v.y; acc.z += v.z; acc.w += v.w;
    }

    __shared__ __align__(16) float4 red[16][64];
    red[g][f] = acc;
    __syncthreads();
    #pragma unroll
    for (int s = 8; s > 0; s >>= 1) {
        if (g < s) {
            float4 o = red[g + s][f];
            acc.x += o.x; acc.y += o.y; acc.z += o.z; acc.w += o.w;
            red[g][f] = acc;
        }
        __syncthreads();
    }

    if (t < 128) {
        const float* row = (const float*)&red[0][0];   // 256 reduced floats
        float s = row[t];
        float q = row[128 + t];
        float mean = s / (float)NN;
        float var  = q / (float)NN - mean * mean;
        float scale = gamma[t] * rsqrtf(var + 1e-5f);
        float bias  = beta[t] - mean * scale;
        sb[t]       = scale;
        sb[128 + t] = bias;
    }
}

// ---------------------------------------------------------------------------
// K5: out2 = relu(h*scale+bias) @ w2.T  [N,128]->[N,64]
// ---------------------------------------------------------------------------
__global__ __launch_bounds__(256) void k_out(
    const float* __restrict__ h, const float* __restrict__ w2,
    const float* __restrict__ sb, float* __restrict__ out)
{
    __shared__ float w2sh[HC][129];
    __shared__ float hsh[4][128];
    __shared__ float ssh[128], bsh[128];

    const int t = threadIdx.x;
    for (int i = t; i < HC * H2C; i += 256) w2sh[i >> 7][i & 127] = w2[i];
    if (t < 128) { ssh[t] = sb[t]; bsh[t] = sb[128 + t]; }
    __syncthreads();

    const int co = t & 63;
    const int nl = t >> 6;

    for (int base = blockIdx.x * 4; base < NN; base += gridDim.x * 4) {
        __syncthreads();
        #pragma unroll
        for (int i = 0; i < 2; ++i) {
            int idx  = i * 256 + t;
            int node = idx >> 7, j = idx & 127;
            int n = base + node;
            if (n < NN) {
                float v = h[n * H2C + j] * ssh[j] + bsh[j];
                hsh[node][j] = v > 0.f ? v : 0.f;
            }
        }
        __syncthreads();
        int n = base + nl;
        if (n < NN) {
            float acc = 0.f;
            #pragma unroll
            for (int j = 0; j < H2C; ++j) acc += hsh[nl][j] * w2sh[co][j];
            out[n * HC + co] = acc;
        }
    }
}

// ---------------------------------------------------------------------------
extern "C" void kernel_launch(void* const* d_in, const int* in_sizes, int n_in,
                              void* d_out, int out_size, void* d_ws, size_t ws_size,
                              hipStream_t stream) {
    const float* x         = (const float*)d_in[0];
    const float* edge_attr = (const float*)d_in[1];
    const float* w_src     = (const float*)d_in[2];
    const float* w_dst     = (const float*)d_in[3];
    const float* w_edge    = (const float*)d_in[4];
    const float* w1        = (const float*)d_in[5];
    const float* gamma     = (const float*)d_in[6];
    const float* beta      = (const float*)d_in[7];
    const float* w2        = (const float*)d_in[8];
    const int*   eidx      = (const int*)d_in[9];    // [2][E], row 0 = src
    const int*   nbr       = (const int*)d_in[10];   // [N][K]

    float* ws   = (float*)d_ws;
    float* srcf = ws;                    // N*64
    float* dstf = ws + 3200000;          // N*64
    float* outf = ws + 6400000;          // N*64
    float* h    = ws + 9600000;          // N*128
    float* part = ws + 16000000;         // 512*256
    float* sb   = ws + 16131072;         // 256

    hipLaunchKernelGGL(k_node_linear,   dim3(512),   dim3(256),  0, stream,
                       x, w_src, w_dst, srcf, dstf);
    hipLaunchKernelGGL(k_edge_agg_mfma, dim3(12500), dim3(256),  0, stream,
                       srcf, dstf, edge_attr, w_edge, eidx, nbr, outf);
    hipLaunchKernelGGL(k_h_partial,     dim3(512),   dim3(256),  0, stream,
                       outf, w1, h, part);
    hipLaunchKernelGGL(k_bn_finalize,   dim3(1),     dim3(1024), 0, stream,
                       part, 512, gamma, beta, sb);
    hipLaunchKernelGGL(k_out,           dim3(512),   dim3(256),  0, stream,
                       h, w2, sb, (float*)d_out);
}

// Round 4
// 166.551 us; speedup vs baseline: 3.0871x; 1.7359x over previous
//
#include <hip/hip_runtime.h>
#include <hip/hip_bf16.h>
#include <float.h>

#define NN 50000
#define KNB 32
#define INC 128
#define HC 64
#define EDD 32
#define H2C 128
#define NBLK 782   // ceil(50000/64)

typedef __attribute__((ext_vector_type(8))) short bf16x8;
typedef __attribute__((ext_vector_type(4))) float f32x4;

__device__ __forceinline__ short f2bf(float f) {
    unsigned u = __builtin_bit_cast(unsigned, f);
    u += 0x7fffu + ((u >> 16) & 1u);          // RTNE
    return (short)(u >> 16);
}
__device__ __forceinline__ float bf2f(short h) {
    unsigned u = ((unsigned)(unsigned short)h) << 16;
    return __builtin_bit_cast(float, u);
}

// ---------------------------------------------------------------------------
// K0: pre-convert weights to fragment-ordered bf16 hi/lo buffers.
// Frag order: [(kt*NT + nt)*64 + lane]*8 + j ; ch = nt*16 + (lane&15),
// k = kt*32 + (lane>>4)*8 + j.
// ---------------------------------------------------------------------------
__global__ __launch_bounds__(256) void k_prep(
    const float* __restrict__ w_src, const float* __restrict__ w_dst,
    const float* __restrict__ w1, const float* __restrict__ w2,
    short* __restrict__ pAhi, short* __restrict__ pAlo,
    short* __restrict__ p1hi, short* __restrict__ p1lo,
    short* __restrict__ p2hi, short* __restrict__ p2lo)
{
    const int tid = blockIdx.x * 256 + threadIdx.x;
    const int nT  = gridDim.x * 256;
    // WA: combined [w_src; w_dst] : 128ch x 128k, NT=8, 4 kt
    for (int idx = tid; idx < 16384; idx += nT) {
        int kt = (idx >> 12) & 3, nt = (idx >> 9) & 7, lane = (idx >> 3) & 63, j = idx & 7;
        int lr = lane & 15, lg = lane >> 4;
        int ch = nt * 16 + lr, k = kt * 32 + lg * 8 + j;
        float f = (ch < 64) ? w_src[ch * 128 + k] : w_dst[(ch - 64) * 128 + k];
        short hi = f2bf(f);
        pAhi[idx] = hi; pAlo[idx] = f2bf(f - bf2f(hi));
    }
    // W1: 128ch x 64k, NT=8, 2 kt
    for (int idx = tid; idx < 8192; idx += nT) {
        int kt = (idx >> 12) & 1, nt = (idx >> 9) & 7, lane = (idx >> 3) & 63, j = idx & 7;
        int lr = lane & 15, lg = lane >> 4;
        int ch = nt * 16 + lr, k = kt * 32 + lg * 8 + j;
        float f = w1[ch * 64 + k];
        short hi = f2bf(f);
        p1hi[idx] = hi; p1lo[idx] = f2bf(f - bf2f(hi));
    }
    // W2: 64ch x 128k, NT=4, 4 kt
    for (int idx = tid; idx < 8192; idx += nT) {
        int kt = (idx >> 11) & 3, nt = (idx >> 9) & 3, lane = (idx >> 3) & 63, j = idx & 7;
        int lr = lane & 15, lg = lane >> 4;
        int ch = nt * 16 + lr, k = kt * 32 + lg * 8 + j;
        float f = w2[ch * 128 + k];
        short hi = f2bf(f);
        p2hi[idx] = hi; p2lo[idx] = f2bf(f - bf2f(hi));
    }
}

__device__ __forceinline__ void split8(const float* av, bf16x8& ahi, bf16x8& alo) {
    #pragma unroll
    for (int j = 0; j < 8; ++j) {
        short h = f2bf(av[j]);
        ahi[j] = h;
        alo[j] = f2bf(av[j] - bf2f(h));
    }
}

// ---------------------------------------------------------------------------
// K1 (MFMA): [srcf|dstf] = x @ [w_src;w_dst].T   [N,128]x[128,128]
// wave = 16 nodes; 8 ntiles x 4 ktiles; hi/lo split -> 3 MFMAs per tile.
// ---------------------------------------------------------------------------
__global__ __launch_bounds__(256) void k_lin1(
    const float* __restrict__ x, const short* __restrict__ pAhi,
    const short* __restrict__ pAlo, float* __restrict__ srcf,
    float* __restrict__ dstf)
{
    const int lane = threadIdx.x & 63, wave = threadIdx.x >> 6;
    const int lr = lane & 15, lg = lane >> 4;
    const int nb = blockIdx.x * 64 + wave * 16;
    const bf16x8* Bh = (const bf16x8*)pAhi;
    const bf16x8* Bl = (const bf16x8*)pAlo;
    int row = nb + lr; if (row > NN - 1) row = NN - 1;

    f32x4 acc[8];
    #pragma unroll
    for (int i = 0; i < 8; ++i) acc[i] = (f32x4){0.f, 0.f, 0.f, 0.f};

    #pragma unroll
    for (int kt = 0; kt < 4; ++kt) {
        const float* ap = x + (size_t)row * INC + kt * 32 + lg * 8;
        float4 a0 = *(const float4*)ap, a1 = *(const float4*)(ap + 4);
        float av[8] = {a0.x, a0.y, a0.z, a0.w, a1.x, a1.y, a1.z, a1.w};
        bf16x8 ahi, alo;
        split8(av, ahi, alo);
        #pragma unroll
        for (int nt = 0; nt < 8; ++nt) {
            bf16x8 bh = Bh[(kt * 8 + nt) * 64 + lane];
            bf16x8 bl = Bl[(kt * 8 + nt) * 64 + lane];
            acc[nt] = __builtin_amdgcn_mfma_f32_16x16x32_bf16(ahi, bl, acc[nt], 0, 0, 0);
            acc[nt] = __builtin_amdgcn_mfma_f32_16x16x32_bf16(alo, bh, acc[nt], 0, 0, 0);
            acc[nt] = __builtin_amdgcn_mfma_f32_16x16x32_bf16(ahi, bh, acc[nt], 0, 0, 0);
        }
    }
    #pragma unroll
    for (int nt = 0; nt < 8; ++nt)
        #pragma unroll
        for (int q = 0; q < 4; ++q) {
            int node = nb + lg * 4 + q;
            if (node < NN) {
                float v = acc[nt][q];
                if (nt < 4) srcf[node * HC + nt * 16 + lr] = v;
                else        dstf[node * HC + (nt - 4) * 16 + lr] = v;
            }
        }
}

// ---------------------------------------------------------------------------
// K2 (MFMA): fused edge projection + ReLU+eps + per-node softmax aggregation.
// (unchanged from R2)
// ---------------------------------------------------------------------------
__global__ __launch_bounds__(256) void k_edge_agg_mfma(
    const float* __restrict__ srcf, const float* __restrict__ dstf,
    const float* __restrict__ edge_attr, const float* __restrict__ w_edge,
    const int* __restrict__ esrc, const int* __restrict__ nbr,
    float* __restrict__ outf)
{
    const int lane = threadIdx.x & 63;
    const int wave = threadIdx.x >> 6;
    const int n    = blockIdx.x * 4 + wave;

    const int lr = lane & 15;
    const int lg = lane >> 4;

    bf16x8 bfrag[4];
    #pragma unroll
    for (int nt = 0; nt < 4; ++nt) {
        const float* wp = &w_edge[(nt * 16 + lr) * EDD + lg * 8];
        float4 w0 = *(const float4*)wp;
        float4 w1v = *(const float4*)(wp + 4);
        bfrag[nt][0] = f2bf(w0.x); bfrag[nt][1] = f2bf(w0.y);
        bfrag[nt][2] = f2bf(w0.z); bfrag[nt][3] = f2bf(w0.w);
        bfrag[nt][4] = f2bf(w1v.x); bfrag[nt][5] = f2bf(w1v.y);
        bfrag[nt][6] = f2bf(w1v.z); bfrag[nt][7] = f2bf(w1v.w);
    }

    const float* ab = edge_attr + (size_t)n * KNB * EDD;
    bf16x8 afrag[2];
    #pragma unroll
    for (int mt = 0; mt < 2; ++mt) {
        const float* ap = ab + (mt * 16 + lr) * EDD + lg * 8;
        float4 a0 = *(const float4*)ap;
        float4 a1 = *(const float4*)(ap + 4);
        afrag[mt][0] = f2bf(a0.x); afrag[mt][1] = f2bf(a0.y);
        afrag[mt][2] = f2bf(a0.z); afrag[mt][3] = f2bf(a0.w);
        afrag[mt][4] = f2bf(a1.x); afrag[mt][5] = f2bf(a1.y);
        afrag[mt][6] = f2bf(a1.z); afrag[mt][7] = f2bf(a1.w);
    }

    int nbv = nbr[n * KNB + (lane & 31)];
    unsigned long long bm = __ballot((lane < 32) && (nbv >= 0));
    unsigned int vmask = (unsigned int)bm;

    int sidx[2][4];
    #pragma unroll
    for (int mt = 0; mt < 2; ++mt)
        #pragma unroll
        for (int r = 0; r < 4; ++r)
            sidx[mt][r] = esrc[n * KNB + mt * 16 + lg * 4 + r];

    f32x4 p[2][4];
    #pragma unroll
    for (int mt = 0; mt < 2; ++mt)
        #pragma unroll
        for (int nt = 0; nt < 4; ++nt) {
            f32x4 z = {0.f, 0.f, 0.f, 0.f};
            p[mt][nt] = __builtin_amdgcn_mfma_f32_16x16x32_bf16(
                afrag[mt], bfrag[nt], z, 0, 0, 0);
        }

    float msg[2][4][4];
    float vf[2][4];
    #pragma unroll
    for (int mt = 0; mt < 2; ++mt)
        #pragma unroll
        for (int r = 0; r < 4; ++r) {
            int k = mt * 16 + lg * 4 + r;
            vf[mt][r] = ((vmask >> k) & 1u) ? 1.f : 0.f;
            const float* sp = &srcf[(size_t)sidx[mt][r] * HC + lr];
            #pragma unroll
            for (int nt = 0; nt < 4; ++nt) {
                float xj = sp[nt * 16];
                float m = p[mt][nt][r] + xj;
                msg[mt][r][nt] = fmaxf(m, 0.f) + 1e-7f;
            }
        }

    float res[4];
    #pragma unroll
    for (int nt = 0; nt < 4; ++nt) {
        float lm = -FLT_MAX;
        #pragma unroll
        for (int mt = 0; mt < 2; ++mt)
            #pragma unroll
            for (int r = 0; r < 4; ++r) {
                float v = (vf[mt][r] > 0.f) ? msg[mt][r][nt] : -FLT_MAX;
                lm = fmaxf(lm, v);
            }
        lm = fmaxf(lm, __shfl_xor(lm, 16, 64));
        lm = fmaxf(lm, __shfl_xor(lm, 32, 64));
        float se = 0.f, ws = 0.f;
        #pragma unroll
        for (int mt = 0; mt < 2; ++mt)
            #pragma unroll
            for (int r = 0; r < 4; ++r) {
                float t = __expf(msg[mt][r][nt] - lm) * vf[mt][r];
                se += t;
                ws += msg[mt][r][nt] * t;
            }
        se += __shfl_xor(se, 16, 64); ws += __shfl_xor(ws, 16, 64);
        se += __shfl_xor(se, 32, 64); ws += __shfl_xor(ws, 32, 64);
        res[nt] = ws / (se + 1e-16f);
    }

    float r01 = (lg & 1) ? res[1] : res[0];
    float r23 = (lg & 1) ? res[3] : res[2];
    float rr  = (lg & 2) ? r23 : r01;
    outf[n * HC + lane] = rr + dstf[n * HC + lane];
}

// ---------------------------------------------------------------------------
// K3 (MFMA): h = out @ w1.T  [N,64]->[N,128]  + per-block BN partials.
// ---------------------------------------------------------------------------
__global__ __launch_bounds__(256) void k_lin2(
    const float* __restrict__ outf, const short* __restrict__ p1hi,
    const short* __restrict__ p1lo, float* __restrict__ h,
    float* __restrict__ partials)
{
    __shared__ float ps[128 * 16], pq[128 * 16];
    const int t = threadIdx.x;
    const int lane = t & 63, wave = t >> 6;
    const int lr = lane & 15, lg = lane >> 4;
    const int nb = blockIdx.x * 64 + wave * 16;
    const bf16x8* Bh = (const bf16x8*)p1hi;
    const bf16x8* Bl = (const bf16x8*)p1lo;
    int row = nb + lr; if (row > NN - 1) row = NN - 1;

    f32x4 acc[8];
    #pragma unroll
    for (int i = 0; i < 8; ++i) acc[i] = (f32x4){0.f, 0.f, 0.f, 0.f};

    #pragma unroll
    for (int kt = 0; kt < 2; ++kt) {
        const float* ap = outf + (size_t)row * HC + kt * 32 + lg * 8;
        float4 a0 = *(const float4*)ap, a1 = *(const float4*)(ap + 4);
        float av[8] = {a0.x, a0.y, a0.z, a0.w, a1.x, a1.y, a1.z, a1.w};
        bf16x8 ahi, alo;
        split8(av, ahi, alo);
        #pragma unroll
        for (int nt = 0; nt < 8; ++nt) {
            bf16x8 bh = Bh[(kt * 8 + nt) * 64 + lane];
            bf16x8 bl = Bl[(kt * 8 + nt) * 64 + lane];
            acc[nt] = __builtin_amdgcn_mfma_f32_16x16x32_bf16(ahi, bl, acc[nt], 0, 0, 0);
            acc[nt] = __builtin_amdgcn_mfma_f32_16x16x32_bf16(alo, bh, acc[nt], 0, 0, 0);
            acc[nt] = __builtin_amdgcn_mfma_f32_16x16x32_bf16(ahi, bh, acc[nt], 0, 0, 0);
        }
    }

    #pragma unroll
    for (int nt = 0; nt < 8; ++nt) {
        float s = 0.f, q = 0.f;
        #pragma unroll
        for (int qq = 0; qq < 4; ++qq) {
            int node = nb + lg * 4 + qq;
            float v = acc[nt][qq];
            if (node < NN) {
                h[node * H2C + nt * 16 + lr] = v;
                s += v;
                q += v * v;
            }
        }
        ps[(nt * 16 + lr) * 16 + wave * 4 + lg] = s;
        pq[(nt * 16 + lr) * 16 + wave * 4 + lg] = q;
    }
    __syncthreads();
    if (t < 128) {
        float s = 0.f, q = 0.f;
        #pragma unroll
        for (int i = 0; i < 16; ++i) { s += ps[t * 16 + i]; q += pq[t * 16 + i]; }
        partials[blockIdx.x * 256 + t]       = s;
        partials[blockIdx.x * 256 + 128 + t] = q;
    }
}

// ---------------------------------------------------------------------------
// K4: reduce partials -> BN scale/bias (1024 threads, vectorized).
// ---------------------------------------------------------------------------
__global__ __launch_bounds__(1024) void k_bn_finalize(
    const float* __restrict__ partials, int nblk,
    const float* __restrict__ gamma, const float* __restrict__ beta,
    float* __restrict__ sb)
{
    const int t = threadIdx.x;
    const int f = t & 63;
    const int g = t >> 6;

    float4 acc = {0.f, 0.f, 0.f, 0.f};
    for (int b = g; b < nblk; b += 16) {
        float4 v = *(const float4*)&partials[b * 256 + f * 4];
        acc.x += v.x; acc.y += v.y; acc.z += v.z; acc.w += v.w;
    }

    __shared__ __align__(16) float4 red[16][64];
    red[g][f] = acc;
    __syncthreads();
    #pragma unroll
    for (int s = 8; s > 0; s >>= 1) {
        if (g < s) {
            float4 o = red[g + s][f];
            acc.x += o.x; acc.y += o.y; acc.z += o.z; acc.w += o.w;
            red[g][f] = acc;
        }
        __syncthreads();
    }

    if (t < 128) {
        const float* row = (const float*)&red[0][0];
        float s = row[t];
        float q = row[128 + t];
        float mean = s / (float)NN;
        float var  = q / (float)NN - mean * mean;
        float scale = gamma[t] * rsqrtf(var + 1e-5f);
        float bias  = beta[t] - mean * scale;
        sb[t]       = scale;
        sb[128 + t] = bias;
    }
}

// ---------------------------------------------------------------------------
// K5 (MFMA): out2 = relu(h*scale+bias) @ w2.T  [N,128]->[N,64]
// ---------------------------------------------------------------------------
__global__ __launch_bounds__(256) void k_lin3(
    const float* __restrict__ h, const short* __restrict__ p2hi,
    const short* __restrict__ p2lo, const float* __restrict__ sb,
    float* __restrict__ out)
{
    const int lane = threadIdx.x & 63, wave = threadIdx.x >> 6;
    const int lr = lane & 15, lg = lane >> 4;
    const int nb = blockIdx.x * 64 + wave * 16;
    const bf16x8* Bh = (const bf16x8*)p2hi;
    const bf16x8* Bl = (const bf16x8*)p2lo;
    int row = nb + lr; if (row > NN - 1) row = NN - 1;

    f32x4 acc[4];
    #pragma unroll
    for (int i = 0; i < 4; ++i) acc[i] = (f32x4){0.f, 0.f, 0.f, 0.f};

    #pragma unroll
    for (int kt = 0; kt < 4; ++kt) {
        const int k0 = kt * 32 + lg * 8;
        float4 sc0 = *(const float4*)&sb[k0],       sc1 = *(const float4*)&sb[k0 + 4];
        float4 bi0 = *(const float4*)&sb[128 + k0], bi1 = *(const float4*)&sb[128 + k0 + 4];
        const float* ap = h + (size_t)row * H2C + k0;
        float4 a0 = *(const float4*)ap, a1 = *(const float4*)(ap + 4);
        float av[8]  = {a0.x, a0.y, a0.z, a0.w, a1.x, a1.y, a1.z, a1.w};
        float scv[8] = {sc0.x, sc0.y, sc0.z, sc0.w, sc1.x, sc1.y, sc1.z, sc1.w};
        float biv[8] = {bi0.x, bi0.y, bi0.z, bi0.w, bi1.x, bi1.y, bi1.z, bi1.w};
        float rv[8];
        #pragma unroll
        for (int j = 0; j < 8; ++j) {
            float v = av[j] * scv[j] + biv[j];
            rv[j] = v > 0.f ? v : 0.f;
        }
        bf16x8 ahi, alo;
        split8(rv, ahi, alo);
        #pragma unroll
        for (int nt = 0; nt < 4; ++nt) {
            bf16x8 bh = Bh[(kt * 4 + nt) * 64 + lane];
            bf16x8 bl = Bl[(kt * 4 + nt) * 64 + lane];
            acc[nt] = __builtin_amdgcn_mfma_f32_16x16x32_bf16(ahi, bl, acc[nt], 0, 0, 0);
            acc[nt] = __builtin_amdgcn_mfma_f32_16x16x32_bf16(alo, bh, acc[nt], 0, 0, 0);
            acc[nt] = __builtin_amdgcn_mfma_f32_16x16x32_bf16(ahi, bh, acc[nt], 0, 0, 0);
        }
    }
    #pragma unroll
    for (int nt = 0; nt < 4; ++nt)
        #pragma unroll
        for (int q = 0; q < 4; ++q) {
            int node = nb + lg * 4 + q;
            if (node < NN) out[node * HC + nt * 16 + lr] = acc[nt][q];
        }
}

// ---------------------------------------------------------------------------
extern "C" void kernel_launch(void* const* d_in, const int* in_sizes, int n_in,
                              void* d_out, int out_size, void* d_ws, size_t ws_size,
                              hipStream_t stream) {
    const float* x         = (const float*)d_in[0];
    const float* edge_attr = (const float*)d_in[1];
    const float* w_src     = (const float*)d_in[2];
    const float* w_dst     = (const float*)d_in[3];
    const float* w_edge    = (const float*)d_in[4];
    const float* w1        = (const float*)d_in[5];
    const float* gamma     = (const float*)d_in[6];
    const float* beta      = (const float*)d_in[7];
    const float* w2        = (const float*)d_in[8];
    const int*   eidx      = (const int*)d_in[9];    // [2][E], row 0 = src
    const int*   nbr       = (const int*)d_in[10];   // [N][K]

    float* ws   = (float*)d_ws;
    float* srcf = ws;                    // N*64
    float* dstf = ws + 3200000;          // N*64
    float* outf = ws + 6400000;          // N*64
    float* h    = ws + 9600000;          // N*128
    float* part = ws + 16000000;         // NBLK*256 = 200192
    float* sb   = ws + 16250000;         // 256
    short* sp   = (short*)(ws + 16300000);
    short* pAhi = sp;                    // 16384 shorts
    short* pAlo = sp + 16384;
    short* p1hi = sp + 32768;            // 8192
    short* p1lo = sp + 40960;
    short* p2hi = sp + 49152;            // 8192
    short* p2lo = sp + 57344;

    hipLaunchKernelGGL(k_prep,          dim3(32),    dim3(256),  0, stream,
                       w_src, w_dst, w1, w2, pAhi, pAlo, p1hi, p1lo, p2hi, p2lo);
    hipLaunchKernelGGL(k_lin1,          dim3(NBLK),  dim3(256),  0, stream,
                       x, pAhi, pAlo, srcf, dstf);
    hipLaunchKernelGGL(k_edge_agg_mfma, dim3(12500), dim3(256),  0, stream,
                       srcf, dstf, edge_attr, w_edge, eidx, nbr, outf);
    hipLaunchKernelGGL(k_lin2,          dim3(NBLK),  dim3(256),  0, stream,
                       outf, p1hi, p1lo, h, part);
    hipLaunchKernelGGL(k_bn_finalize,   dim3(1),     dim3(1024), 0, stream,
                       part, NBLK, gamma, beta, sb);
    hipLaunchKernelGGL(k_lin3,          dim3(NBLK),  dim3(256),  0, stream,
                       h, p2hi, p2lo, sb, (float*)d_out);
}

// Round 5
// 152.586 us; speedup vs baseline: 3.3696x; 1.0915x over previous
//
#include <hip/hip_runtime.h>
#include <hip/hip_bf16.h>
#include <float.h>

#define NN 50000
#define KNB 32
#define INC 128
#define HC 64
#define EDD 32
#define H2C 128
#define NBLK 782   // ceil(50000/64)

typedef __attribute__((ext_vector_type(8))) short bf16x8;
typedef __attribute__((ext_vector_type(4))) float f32x4;

__device__ __forceinline__ short f2bf(float f) {
    unsigned u = __builtin_bit_cast(unsigned, f);
    u += 0x7fffu + ((u >> 16) & 1u);          // RTNE
    return (short)(u >> 16);
}
__device__ __forceinline__ float bf2f(short h) {
    unsigned u = ((unsigned)(unsigned short)h) << 16;
    return __builtin_bit_cast(float, u);
}

// ---------------------------------------------------------------------------
// K0: pre-convert weights to fragment-ordered bf16 buffers.
// Frag order: [(kt*NT + nt)*64 + lane]*8 + j ; ch = nt*16 + (lane&15),
// k = kt*32 + (lane>>4)*8 + j.  Also w_edge single-precision bf16 frags.
// ---------------------------------------------------------------------------
__global__ __launch_bounds__(256) void k_prep(
    const float* __restrict__ w_src, const float* __restrict__ w_dst,
    const float* __restrict__ w1, const float* __restrict__ w2,
    const float* __restrict__ w_edge,
    short* __restrict__ pAhi, short* __restrict__ pAlo,
    short* __restrict__ p1hi, short* __restrict__ p1lo,
    short* __restrict__ p2hi, short* __restrict__ p2lo,
    short* __restrict__ pE)
{
    const int tid = blockIdx.x * 256 + threadIdx.x;
    const int nT  = gridDim.x * 256;
    // WA: combined [w_src; w_dst] : 128ch x 128k, NT=8, 4 kt
    for (int idx = tid; idx < 16384; idx += nT) {
        int kt = (idx >> 12) & 3, nt = (idx >> 9) & 7, lane = (idx >> 3) & 63, j = idx & 7;
        int lr = lane & 15, lg = lane >> 4;
        int ch = nt * 16 + lr, k = kt * 32 + lg * 8 + j;
        float f = (ch < 64) ? w_src[ch * 128 + k] : w_dst[(ch - 64) * 128 + k];
        short hi = f2bf(f);
        pAhi[idx] = hi; pAlo[idx] = f2bf(f - bf2f(hi));
    }
    // W1: 128ch x 64k, NT=8, 2 kt
    for (int idx = tid; idx < 8192; idx += nT) {
        int kt = (idx >> 12) & 1, nt = (idx >> 9) & 7, lane = (idx >> 3) & 63, j = idx & 7;
        int lr = lane & 15, lg = lane >> 4;
        int ch = nt * 16 + lr, k = kt * 32 + lg * 8 + j;
        float f = w1[ch * 64 + k];
        short hi = f2bf(f);
        p1hi[idx] = hi; p1lo[idx] = f2bf(f - bf2f(hi));
    }
    // W2: 64ch x 128k, NT=4, 4 kt
    for (int idx = tid; idx < 8192; idx += nT) {
        int kt = (idx >> 11) & 3, nt = (idx >> 9) & 3, lane = (idx >> 3) & 63, j = idx & 7;
        int lr = lane & 15, lg = lane >> 4;
        int ch = nt * 16 + lr, k = kt * 32 + lg * 8 + j;
        float f = w2[ch * 128 + k];
        short hi = f2bf(f);
        p2hi[idx] = hi; p2lo[idx] = f2bf(f - bf2f(hi));
    }
    // w_edge: 64ch x 32k, NT=4, 1 kt (single bf16, no hi/lo)
    for (int idx = tid; idx < 2048; idx += nT) {
        int nt = (idx >> 9) & 3, lane = (idx >> 3) & 63, j = idx & 7;
        int lr = lane & 15, lg = lane >> 4;
        int ch = nt * 16 + lr, k = lg * 8 + j;
        pE[idx] = f2bf(w_edge[ch * EDD + k]);
    }
}

__device__ __forceinline__ void split8(const float* av, bf16x8& ahi, bf16x8& alo) {
    #pragma unroll
    for (int j = 0; j < 8; ++j) {
        short h = f2bf(av[j]);
        ahi[j] = h;
        alo[j] = f2bf(av[j] - bf2f(h));
    }
}

// ---------------------------------------------------------------------------
// K1 (MFMA): [srcP|dstf] = x @ [w_src;w_dst].T   [N,128]x[128,128]
// srcP is written PERMUTED: srcP[node*64 + lr*4 + nt] = src_ch[nt*16+lr]
// so K2 can gather one float4 per (edge,lane).
// ---------------------------------------------------------------------------
__global__ __launch_bounds__(256) void k_lin1(
    const float* __restrict__ x, const short* __restrict__ pAhi,
    const short* __restrict__ pAlo, float* __restrict__ srcP,
    float* __restrict__ dstf)
{
    const int lane = threadIdx.x & 63, wave = threadIdx.x >> 6;
    const int lr = lane & 15, lg = lane >> 4;
    const int nb = blockIdx.x * 64 + wave * 16;
    const bf16x8* Bh = (const bf16x8*)pAhi;
    const bf16x8* Bl = (const bf16x8*)pAlo;
    int row = nb + lr; if (row > NN - 1) row = NN - 1;

    f32x4 acc[8];
    #pragma unroll
    for (int i = 0; i < 8; ++i) acc[i] = (f32x4){0.f, 0.f, 0.f, 0.f};

    #pragma unroll
    for (int kt = 0; kt < 4; ++kt) {
        const float* ap = x + (size_t)row * INC + kt * 32 + lg * 8;
        float4 a0 = *(const float4*)ap, a1 = *(const float4*)(ap + 4);
        float av[8] = {a0.x, a0.y, a0.z, a0.w, a1.x, a1.y, a1.z, a1.w};
        bf16x8 ahi, alo;
        split8(av, ahi, alo);
        #pragma unroll
        for (int nt = 0; nt < 8; ++nt) {
            bf16x8 bh = Bh[(kt * 8 + nt) * 64 + lane];
            bf16x8 bl = Bl[(kt * 8 + nt) * 64 + lane];
            acc[nt] = __builtin_amdgcn_mfma_f32_16x16x32_bf16(ahi, bl, acc[nt], 0, 0, 0);
            acc[nt] = __builtin_amdgcn_mfma_f32_16x16x32_bf16(alo, bh, acc[nt], 0, 0, 0);
            acc[nt] = __builtin_amdgcn_mfma_f32_16x16x32_bf16(ahi, bh, acc[nt], 0, 0, 0);
        }
    }
    #pragma unroll
    for (int nt = 0; nt < 8; ++nt)
        #pragma unroll
        for (int q = 0; q < 4; ++q) {
            int node = nb + lg * 4 + q;
            if (node < NN) {
                float v = acc[nt][q];
                if (nt < 4) srcP[node * HC + lr * 4 + nt] = v;     // permuted
                else        dstf[node * HC + (nt - 4) * 16 + lr] = v;
            }
        }
}

// ---------------------------------------------------------------------------
// K2 (MFMA): fused edge projection + ReLU+eps + per-node softmax aggregation.
// One wave per node. VMEM per wave: 2 int4 (esrc) + 1 (nbr) + 4 f4 (attr)
// + 4 dwx4 (bfrag) + 8 f4 (srcP gather) + 1 (dstf) + 1 store.
// ---------------------------------------------------------------------------
__global__ __launch_bounds__(256) void k_edge_agg_mfma(
    const float* __restrict__ srcP, const float* __restrict__ dstf,
    const float* __restrict__ edge_attr, const short* __restrict__ pE,
    const int* __restrict__ esrc, const int* __restrict__ nbr,
    float* __restrict__ outf)
{
    const int lane = threadIdx.x & 63;
    const int wave = threadIdx.x >> 6;
    const int n    = blockIdx.x * 4 + wave;

    const int lr = lane & 15;
    const int lg = lane >> 4;

    // source indices: lane's 8 edge slots, 2 x int4
    int4 sv0 = *(const int4*)&esrc[n * KNB + lg * 4];
    int4 sv1 = *(const int4*)&esrc[n * KNB + 16 + lg * 4];
    int sidx[2][4] = {{sv0.x, sv0.y, sv0.z, sv0.w}, {sv1.x, sv1.y, sv1.z, sv1.w}};

    // validity mask (wave-uniform)
    int nbv = nbr[n * KNB + (lane & 31)];
    unsigned long long bm = __ballot((lane < 32) && (nbv >= 0));
    unsigned int vmask = (unsigned int)bm;

    // gather x_j fragments: one float4 per (mt,r)
    float4 xjv[2][4];
    #pragma unroll
    for (int mt = 0; mt < 2; ++mt)
        #pragma unroll
        for (int r = 0; r < 4; ++r)
            xjv[mt][r] = *(const float4*)&srcP[(size_t)sidx[mt][r] * HC + lr * 4];

    // A fragments: this node's 32x32 edge_attr tile (contiguous 4KB)
    const float* ab = edge_attr + (size_t)n * KNB * EDD;
    bf16x8 afrag[2];
    #pragma unroll
    for (int mt = 0; mt < 2; ++mt) {
        const float* ap = ab + (mt * 16 + lr) * EDD + lg * 8;
        float4 a0 = *(const float4*)ap;
        float4 a1 = *(const float4*)(ap + 4);
        float av[8] = {a0.x, a0.y, a0.z, a0.w, a1.x, a1.y, a1.z, a1.w};
        bf16x8 dummy;
        split8(av, afrag[mt], dummy);   // only hi used
        (void)dummy;
    }

    // B fragments: prepped bf16 (raw 16B loads)
    const bf16x8* Bp = (const bf16x8*)pE;
    bf16x8 bfrag[4];
    #pragma unroll
    for (int nt = 0; nt < 4; ++nt) bfrag[nt] = Bp[nt * 64 + lane];

    // projection: p[mt][nt][r] = P[16mt + lg*4 + r][16nt + lr]
    f32x4 p[2][4];
    #pragma unroll
    for (int mt = 0; mt < 2; ++mt)
        #pragma unroll
        for (int nt = 0; nt < 4; ++nt) {
            f32x4 z = {0.f, 0.f, 0.f, 0.f};
            p[mt][nt] = __builtin_amdgcn_mfma_f32_16x16x32_bf16(
                afrag[mt], bfrag[nt], z, 0, 0, 0);
        }

    // msg = relu(x_j + proj) + eps
    float msg[2][4][4];   // [mt][r][nt]
    float vf[2][4];
    #pragma unroll
    for (int mt = 0; mt < 2; ++mt)
        #pragma unroll
        for (int r = 0; r < 4; ++r) {
            int k = mt * 16 + lg * 4 + r;
            vf[mt][r] = ((vmask >> k) & 1u) ? 1.f : 0.f;
            float xj[4] = {xjv[mt][r].x, xjv[mt][r].y, xjv[mt][r].z, xjv[mt][r].w};
            #pragma unroll
            for (int nt = 0; nt < 4; ++nt) {
                float m = p[mt][nt][r] + xj[nt];
                msg[mt][r][nt] = fmaxf(m, 0.f) + 1e-7f;
            }
        }

    // per-channel softmax-weighted mean; channel c = 16*nt + lr lives in
    // lanes {lr, lr+16, lr+32, lr+48} -> reduce via shfl_xor 16,32
    float res[4];
    #pragma unroll
    for (int nt = 0; nt < 4; ++nt) {
        float lm = -FLT_MAX;
        #pragma unroll
        for (int mt = 0; mt < 2; ++mt)
            #pragma unroll
            for (int r = 0; r < 4; ++r) {
                float v = (vf[mt][r] > 0.f) ? msg[mt][r][nt] : -FLT_MAX;
                lm = fmaxf(lm, v);
            }
        lm = fmaxf(lm, __shfl_xor(lm, 16, 64));
        lm = fmaxf(lm, __shfl_xor(lm, 32, 64));
        float se = 0.f, ws = 0.f;
        #pragma unroll
        for (int mt = 0; mt < 2; ++mt)
            #pragma unroll
            for (int r = 0; r < 4; ++r) {
                float t = __expf(msg[mt][r][nt] - lm) * vf[mt][r];
                se += t;
                ws += msg[mt][r][nt] * t;
            }
        se += __shfl_xor(se, 16, 64); ws += __shfl_xor(ws, 16, 64);
        se += __shfl_xor(se, 32, 64); ws += __shfl_xor(ws, 32, 64);
        res[nt] = ws / (se + 1e-16f);
    }

    float r01 = (lg & 1) ? res[1] : res[0];
    float r23 = (lg & 1) ? res[3] : res[2];
    float rr  = (lg & 2) ? r23 : r01;
    outf[n * HC + lane] = rr + dstf[n * HC + lane];
}

// ---------------------------------------------------------------------------
// K3 (MFMA): h = out @ w1.T  [N,64]->[N,128]  + per-block BN partials.
// ---------------------------------------------------------------------------
__global__ __launch_bounds__(256) void k_lin2(
    const float* __restrict__ outf, const short* __restrict__ p1hi,
    const short* __restrict__ p1lo, float* __restrict__ h,
    float* __restrict__ partials)
{
    __shared__ float ps[128 * 16], pq[128 * 16];
    const int t = threadIdx.x;
    const int lane = t & 63, wave = t >> 6;
    const int lr = lane & 15, lg = lane >> 4;
    const int nb = blockIdx.x * 64 + wave * 16;
    const bf16x8* Bh = (const bf16x8*)p1hi;
    const bf16x8* Bl = (const bf16x8*)p1lo;
    int row = nb + lr; if (row > NN - 1) row = NN - 1;

    f32x4 acc[8];
    #pragma unroll
    for (int i = 0; i < 8; ++i) acc[i] = (f32x4){0.f, 0.f, 0.f, 0.f};

    #pragma unroll
    for (int kt = 0; kt < 2; ++kt) {
        const float* ap = outf + (size_t)row * HC + kt * 32 + lg * 8;
        float4 a0 = *(const float4*)ap, a1 = *(const float4*)(ap + 4);
        float av[8] = {a0.x, a0.y, a0.z, a0.w, a1.x, a1.y, a1.z, a1.w};
        bf16x8 ahi, alo;
        split8(av, ahi, alo);
        #pragma unroll
        for (int nt = 0; nt < 8; ++nt) {
            bf16x8 bh = Bh[(kt * 8 + nt) * 64 + lane];
            bf16x8 bl = Bl[(kt * 8 + nt) * 64 + lane];
            acc[nt] = __builtin_amdgcn_mfma_f32_16x16x32_bf16(ahi, bl, acc[nt], 0, 0, 0);
            acc[nt] = __builtin_amdgcn_mfma_f32_16x16x32_bf16(alo, bh, acc[nt], 0, 0, 0);
            acc[nt] = __builtin_amdgcn_mfma_f32_16x16x32_bf16(ahi, bh, acc[nt], 0, 0, 0);
        }
    }

    #pragma unroll
    for (int nt = 0; nt < 8; ++nt) {
        float s = 0.f, q = 0.f;
        #pragma unroll
        for (int qq = 0; qq < 4; ++qq) {
            int node = nb + lg * 4 + qq;
            float v = acc[nt][qq];
            if (node < NN) {
                h[node * H2C + nt * 16 + lr] = v;
                s += v;
                q += v * v;
            }
        }
        ps[(nt * 16 + lr) * 16 + wave * 4 + lg] = s;
        pq[(nt * 16 + lr) * 16 + wave * 4 + lg] = q;
    }
    __syncthreads();
    if (t < 128) {
        float s = 0.f, q = 0.f;
        #pragma unroll
        for (int i = 0; i < 16; ++i) { s += ps[t * 16 + i]; q += pq[t * 16 + i]; }
        partials[blockIdx.x * 256 + t]       = s;
        partials[blockIdx.x * 256 + 128 + t] = q;
    }
}

// ---------------------------------------------------------------------------
// K4: reduce partials -> BN scale/bias (1024 threads, vectorized).
// ---------------------------------------------------------------------------
__global__ __launch_bounds__(1024) void k_bn_finalize(
    const float* __restrict__ partials, int nblk,
    const float* __restrict__ gamma, const float* __restrict__ beta,
    float* __restrict__ sb)
{
    const int t = threadIdx.x;
    const int f = t & 63;
    const int g = t >> 6;

    float4 acc = {0.f, 0.f, 0.f, 0.f};
    for (int b = g; b < nblk; b += 16) {
        float4 v = *(const float4*)&partials[b * 256 + f * 4];
        acc.x += v.x; acc.y += v.y; acc.z += v.z; acc.w += v.w;
    }

    __shared__ __align__(16) float4 red[16][64];
    red[g][f] = acc;
    __syncthreads();
    #pragma unroll
    for (int s = 8; s > 0; s >>= 1) {
        if (g < s) {
            float4 o = red[g + s][f];
            acc.x += o.x; acc.y += o.y; acc.z += o.z; acc.w += o.w;
            red[g][f] = acc;
        }
        __syncthreads();
    }

    if (t < 128) {
        const float* row = (const float*)&red[0][0];
        float s = row[t];
        float q = row[128 + t];
        float mean = s / (float)NN;
        float var  = q / (float)NN - mean * mean;
        float scale = gamma[t] * rsqrtf(var + 1e-5f);
        float bias  = beta[t] - mean * scale;
        sb[t]       = scale;
        sb[128 + t] = bias;
    }
}

// ---------------------------------------------------------------------------
// K5 (MFMA): out2 = relu(h*scale+bias) @ w2.T  [N,128]->[N,64]
// ---------------------------------------------------------------------------
__global__ __launch_bounds__(256) void k_lin3(
    const float* __restrict__ h, const short* __restrict__ p2hi,
    const short* __restrict__ p2lo, const float* __restrict__ sb,
    float* __restrict__ out)
{
    const int lane = threadIdx.x & 63, wave = threadIdx.x >> 6;
    const int lr = lane & 15, lg = lane >> 4;
    const int nb = blockIdx.x * 64 + wave * 16;
    const bf16x8* Bh = (const bf16x8*)p2hi;
    const bf16x8* Bl = (const bf16x8*)p2lo;
    int row = nb + lr; if (row > NN - 1) row = NN - 1;

    f32x4 acc[4];
    #pragma unroll
    for (int i = 0; i < 4; ++i) acc[i] = (f32x4){0.f, 0.f, 0.f, 0.f};

    #pragma unroll
    for (int kt = 0; kt < 4; ++kt) {
        const int k0 = kt * 32 + lg * 8;
        float4 sc0 = *(const float4*)&sb[k0],       sc1 = *(const float4*)&sb[k0 + 4];
        float4 bi0 = *(const float4*)&sb[128 + k0], bi1 = *(const float4*)&sb[128 + k0 + 4];
        const float* ap = h + (size_t)row * H2C + k0;
        float4 a0 = *(const float4*)ap, a1 = *(const float4*)(ap + 4);
        float av[8]  = {a0.x, a0.y, a0.z, a0.w, a1.x, a1.y, a1.z, a1.w};
        float scv[8] = {sc0.x, sc0.y, sc0.z, sc0.w, sc1.x, sc1.y, sc1.z, sc1.w};
        float biv[8] = {bi0.x, bi0.y, bi0.z, bi0.w, bi1.x, bi1.y, bi1.z, bi1.w};
        float rv[8];
        #pragma unroll
        for (int j = 0; j < 8; ++j) {
            float v = av[j] * scv[j] + biv[j];
            rv[j] = v > 0.f ? v : 0.f;
        }
        bf16x8 ahi, alo;
        split8(rv, ahi, alo);
        #pragma unroll
        for (int nt = 0; nt < 4; ++nt) {
            bf16x8 bh = Bh[(kt * 4 + nt) * 64 + lane];
            bf16x8 bl = Bl[(kt * 4 + nt) * 64 + lane];
            acc[nt] = __builtin_amdgcn_mfma_f32_16x16x32_bf16(ahi, bl, acc[nt], 0, 0, 0);
            acc[nt] = __builtin_amdgcn_mfma_f32_16x16x32_bf16(alo, bh, acc[nt], 0, 0, 0);
            acc[nt] = __builtin_amdgcn_mfma_f32_16x16x32_bf16(ahi, bh, acc[nt], 0, 0, 0);
        }
    }
    #pragma unroll
    for (int nt = 0; nt < 4; ++nt)
        #pragma unroll
        for (int q = 0; q < 4; ++q) {
            int node = nb + lg * 4 + q;
            if (node < NN) out[node * HC + nt * 16 + lr] = acc[nt][q];
        }
}

// ---------------------------------------------------------------------------
extern "C" void kernel_launch(void* const* d_in, const int* in_sizes, int n_in,
                              void* d_out, int out_size, void* d_ws, size_t ws_size,
                              hipStream_t stream) {
    const float* x         = (const float*)d_in[0];
    const float* edge_attr = (const float*)d_in[1];
    const float* w_src     = (const float*)d_in[2];
    const float* w_dst     = (const float*)d_in[3];
    const float* w_edge    = (const float*)d_in[4];
    const float* w1        = (const float*)d_in[5];
    const float* gamma     = (const float*)d_in[6];
    const float* beta      = (const float*)d_in[7];
    const float* w2        = (const float*)d_in[8];
    const int*   eidx      = (const int*)d_in[9];    // [2][E], row 0 = src
    const int*   nbr       = (const int*)d_in[10];   // [N][K]

    float* ws   = (float*)d_ws;
    float* srcP = ws;                    // N*64 (permuted)
    float* dstf = ws + 3200000;          // N*64
    float* outf = ws + 6400000;          // N*64
    float* h    = ws + 9600000;          // N*128
    float* part = ws + 16000000;         // NBLK*256 = 200192
    float* sb   = ws + 16250000;         // 256
    short* sp   = (short*)(ws + 16300000);
    short* pAhi = sp;                    // 16384 shorts
    short* pAlo = sp + 16384;
    short* p1hi = sp + 32768;            // 8192
    short* p1lo = sp + 40960;
    short* p2hi = sp + 49152;            // 8192
    short* p2lo = sp + 57344;
    short* pE   = sp + 65536;            // 2048

    hipLaunchKernelGGL(k_prep,          dim3(32),    dim3(256),  0, stream,
                       w_src, w_dst, w1, w2, w_edge,
                       pAhi, pAlo, p1hi, p1lo, p2hi, p2lo, pE);
    hipLaunchKernelGGL(k_lin1,          dim3(NBLK),  dim3(256),  0, stream,
                       x, pAhi, pAlo, srcP, dstf);
    hipLaunchKernelGGL(k_edge_agg_mfma, dim3(12500), dim3(256),  0, stream,
                       srcP, dstf, edge_attr, pE, eidx, nbr, outf);
    hipLaunchKernelGGL(k_lin2,          dim3(NBLK),  dim3(256),  0, stream,
                       outf, p1hi, p1lo, h, part);
    hipLaunchKernelGGL(k_bn_finalize,   dim3(1),     dim3(1024), 0, stream,
                       part, NBLK, gamma, beta, sb);
    hipLaunchKernelGGL(k_lin3,          dim3(NBLK),  dim3(256),  0, stream,
                       h, p2hi, p2lo, sb, (float*)d_out);
}